// Round 6
// baseline (753.072 us; speedup 1.0000x reference)
//
#include <hip/hip_runtime.h>

#define N_NODES 100000
#define N_EDGES 3200000
#define NF 256
#define HID 64
#define NBLK ((N_NODES + 255) / 256)   // 391 scan blocks
#define CHUNK 16                        // feature chunk (3.2 MB bf16, fits XCD L2)
#define NPASS (HID / CHUNK)             // 4 passes

typedef short short8 __attribute__((ext_vector_type(8)));
typedef float f32x4 __attribute__((ext_vector_type(4)));

__device__ __forceinline__ unsigned short f2bf(float v) {
    unsigned int u = __float_as_uint(v);
    u += 0x7FFFu + ((u >> 16) & 1u);
    return (unsigned short)(u >> 16);
}

// ---------- packed degree: cnt<<24 | fixed-point(ew sum, scale 2^16) ----------
// max degree ~70 (Poisson(32)) << 255; sum(ew)*2^16 < 2^24. 4B atomic halves RMW bytes.
__global__ void degcnt_kernel(const int* __restrict__ ei, const float* __restrict__ ew,
                              unsigned int* __restrict__ packed) {
    int e = blockIdx.x * blockDim.x + threadIdx.x;
    if (e < N_EDGES) {
        int d = ei[N_EDGES + e];
        unsigned int fx = (unsigned int)(ew[e] * 65536.0f);
        atomicAdd(&packed[d], (1u << 24) | fx);
    }
}

// dinv = rsqrt(deg + 1); unpack cnt; per-block sum of cnt -> bsum
__launch_bounds__(256)
__global__ void dinv_kernel(const unsigned int* __restrict__ packed,
                            float* __restrict__ dinv, int* __restrict__ cnt,
                            int* __restrict__ bsum) {
    __shared__ int sh[256];
    int t = threadIdx.x;
    int i = blockIdx.x * 256 + t;
    int c = 0;
    if (i < N_NODES) {
        unsigned int p = packed[i];
        float deg = (float)(p & 0xFFFFFFu) * (1.0f / 65536.0f);
        c = (int)(p >> 24);
        cnt[i] = c;
        dinv[i] = rsqrtf(deg + 1.0f);
    }
    sh[t] = c;
    __syncthreads();
    for (int off = 128; off > 0; off >>= 1) {
        if (t < off) sh[t] += sh[t + off];
        __syncthreads();
    }
    if (t == 0) bsum[blockIdx.x] = sh[0];
}

// ---------- exclusive scan of the 391 block sums (single tiny block) ----------
__launch_bounds__(512)
__global__ void scanb_kernel(int* __restrict__ bsum) {
    __shared__ int sh[512];
    int t = threadIdx.x;
    int v = (t < NBLK) ? bsum[t] : 0;
    sh[t] = v;
    __syncthreads();
    for (int off = 1; off < 512; off <<= 1) {
        int add = (t >= off) ? sh[t - off] : 0;
        __syncthreads();
        sh[t] += add;
        __syncthreads();
    }
    if (t < NBLK) bsum[t] = sh[t] - v;  // exclusive
}

// ---------- block-local scan + offset -> row_ptr, cursor ----------
__launch_bounds__(256)
__global__ void scan2_kernel(const int* __restrict__ cnt, const int* __restrict__ bsum,
                             int* __restrict__ row_ptr, int* __restrict__ cursor) {
    __shared__ int sh[256];
    int t = threadIdx.x;
    int i = blockIdx.x * 256 + t;
    int v = (i < N_NODES) ? cnt[i] : 0;
    sh[t] = v;
    __syncthreads();
    for (int off = 1; off < 256; off <<= 1) {
        int add = (t >= off) ? sh[t - off] : 0;
        __syncthreads();
        sh[t] += add;
        __syncthreads();
    }
    if (i < N_NODES) {
        int excl = bsum[blockIdx.x] + sh[t] - v;
        row_ptr[i] = excl;
        cursor[i] = excl;
    }
    if (i == N_NODES - 1) row_ptr[N_NODES] = N_EDGES;
}

// ---------- scatter edges into CSR: packed (src, weight-bits) 8B writes ----------
__global__ void scatter_kernel(const int* __restrict__ ei, const float* __restrict__ ew,
                               const float* __restrict__ dinv, int* __restrict__ cursor,
                               int2* __restrict__ ebuf) {
    int e = blockIdx.x * blockDim.x + threadIdx.x;
    if (e < N_EDGES) {
        int s = ei[e];
        int d = ei[N_EDGES + e];
        int pos = atomicAdd(&cursor[d], 1);
        float w = dinv[s] * ew[e] * dinv[d];
        ebuf[pos] = make_int2(s, __float_as_int(w));
    }
}

// ---------- one-time W1 swizzle into MFMA B-fragment order (bf16) ----------
__global__ void wswiz_kernel(const float* __restrict__ W, unsigned short* __restrict__ wsw) {
    int idx = blockIdx.x * blockDim.x + threadIdx.x;  // 0 .. 16383
    if (idx < NF * HID) {
        int j = idx & 7;
        int lane = (idx >> 3) & 63;
        int ntile = (idx >> 9) & 3;
        int kiter = idx >> 11;
        int k = kiter * 32 + (lane >> 4) * 8 + j;
        int n = ntile * 16 + (lane & 15);
        wsw[idx] = f2bf(W[k * HID + n]);
    }
}

// ---------- h = x @ W1 via MFMA; output in CHUNK-MAJOR layout ----------
// hc[chunk][row][f], chunk = col/16, f = col&15
__launch_bounds__(256)
__global__ void gemm1_mfma(const float* __restrict__ x, const unsigned short* __restrict__ wsw,
                           unsigned short* __restrict__ hc) {
    int t = threadIdx.x;
    int lane = t & 63;
    int wave = t >> 6;
    int m = lane & 15;
    int quad = lane >> 4;
    int rowbase = blockIdx.x * 64 + wave * 16;

    int row = rowbase + m;
    if (row >= N_NODES) row = N_NODES - 1;

    const short8* wv = (const short8*)wsw;

    f32x4 acc[4] = {{0.f,0.f,0.f,0.f},{0.f,0.f,0.f,0.f},{0.f,0.f,0.f,0.f},{0.f,0.f,0.f,0.f}};

    const float* xrow = x + (size_t)row * NF;
#pragma unroll
    for (int kiter = 0; kiter < 8; ++kiter) {
        int k0 = kiter * 32 + quad * 8;
        float4 xa = *(const float4*)&xrow[k0];
        float4 xb = *(const float4*)&xrow[k0 + 4];
        short8 a;
        a[0] = (short)f2bf(xa.x); a[1] = (short)f2bf(xa.y);
        a[2] = (short)f2bf(xa.z); a[3] = (short)f2bf(xa.w);
        a[4] = (short)f2bf(xb.x); a[5] = (short)f2bf(xb.y);
        a[6] = (short)f2bf(xb.z); a[7] = (short)f2bf(xb.w);
#pragma unroll
        for (int nt = 0; nt < 4; ++nt) {
            short8 b = wv[(kiter * 4 + nt) * 64 + lane];
            acc[nt] = __builtin_amdgcn_mfma_f32_16x16x32_bf16(a, b, acc[nt], 0, 0, 0);
        }
    }

#pragma unroll
    for (int nt = 0; nt < 4; ++nt) {
#pragma unroll
        for (int r = 0; r < 4; ++r) {
            int orow = rowbase + quad * 4 + r;
            if (orow < N_NODES) {
                hc[(size_t)nt * N_NODES * CHUNK + (size_t)orow * CHUNK + m] = f2bf(acc[nt][r]);
            }
        }
    }
}

// ---------- feature-blocked layer-1 aggregation (one pass = one 16-col chunk) ----------
// Wave per dst; lanes = 4 edge-slots x 16 features. h-chunk (3.2 MB) stays L2-hot;
// ebuf streamed with nontemporal loads to avoid evicting it.
__launch_bounds__(256)
__global__ void agg1_pass(const int* __restrict__ row_ptr, const int2* __restrict__ ebuf,
                          const unsigned short* __restrict__ hchunk,  // base of this pass's chunk
                          float* __restrict__ agg, int pass) {
    int lane = threadIdx.x & 63;
    int d = (blockIdx.x * blockDim.x + threadIdx.x) >> 6;
    if (d >= N_NODES) return;

    int start = row_ptr[d];
    int end = row_ptr[d + 1];
    int f = lane & 15;
    int q = lane >> 4;

    float acc = 0.0f;
    for (int base = start; base < end; base += 64) {
        int n = end - base; if (n > 64) n = 64;
        long long raw = 0;
        if (lane < n)
            raw = __builtin_nontemporal_load((const long long*)&ebuf[base + lane]);
        int sx = (int)(raw & 0xFFFFFFFFLL);
        int wy = (int)(raw >> 32);
        int nq = (n + 3) >> 2;
        for (int jj = 0; jj < nq; ++jj) {
            int src_lane = jj * 4 + q;
            int s = __shfl(sx, src_lane);
            float w = __int_as_float(__shfl(wy, src_lane));
            float hv = __uint_as_float((unsigned int)hchunk[(size_t)s * CHUNK + f] << 16);
            acc = fmaf(w, hv, acc);
        }
    }
    // reduce across the 4 edge-slots (quads)
    acc += __shfl_down(acc, 32);
    acc += __shfl_down(acc, 16);
    if (lane < 16) agg[(size_t)d * HID + pass * CHUNK + lane] = acc;
}

// ---------- post layer-1: self-loop + bias + ELU + @W2 -> z ----------
__launch_bounds__(256)
__global__ void post1_kernel(const float* __restrict__ agg, const unsigned short* __restrict__ hc,
                             const float* __restrict__ dinv, const float* __restrict__ b1,
                             const float* __restrict__ W2, float* __restrict__ z) {
    int lane = threadIdx.x & 63;
    int d = (blockIdx.x * blockDim.x + threadIdx.x) >> 6;
    if (d >= N_NODES) return;

    float di = dinv[d];
    float hd = __uint_as_float(
        (unsigned int)hc[((size_t)(lane >> 4) * N_NODES + d) * CHUNK + (lane & 15)] << 16);
    float v = agg[(size_t)d * HID + lane] + di * di * hd + b1[lane];
    v = (v > 0.0f) ? v : (__expf(v) - 1.0f);

    float p = v * W2[lane];
#pragma unroll
    for (int off = 32; off > 0; off >>= 1) p += __shfl_down(p, off);
    if (lane == 0) z[d] = p;
}

// ---------- fused layer-2 aggregation + self-loop + bias + sigmoid ----------
__launch_bounds__(256)
__global__ void fused2_kernel(const int* __restrict__ row_ptr, const int2* __restrict__ ebuf,
                              const float* __restrict__ z, const float* __restrict__ dinv,
                              const float* __restrict__ b2, float* __restrict__ out) {
    int lane = threadIdx.x & 63;
    int d = (blockIdx.x * blockDim.x + threadIdx.x) >> 6;
    if (d >= N_NODES) return;

    int start = row_ptr[d];
    int end = row_ptr[d + 1];

    float acc = 0.0f;
    for (int i = start + lane; i < end; i += 64) {
        int2 e = ebuf[i];
        acc = fmaf(__int_as_float(e.y), z[e.x], acc);
    }
#pragma unroll
    for (int off = 32; off > 0; off >>= 1) acc += __shfl_down(acc, off);

    if (lane == 0) {
        float di = dinv[d];
        float v = acc + di * di * z[d] + b2[0];
        out[d] = 1.0f / (1.0f + __expf(-v));
    }
}

extern "C" void kernel_launch(void* const* d_in, const int* in_sizes, int n_in,
                              void* d_out, int out_size, void* d_ws, size_t ws_size,
                              hipStream_t stream) {
    const float* x  = (const float*)d_in[0];
    const int*   ei = (const int*)d_in[1];
    const float* ew = (const float*)d_in[2];
    const float* W1 = (const float*)d_in[3];
    const float* b1 = (const float*)d_in[4];
    const float* W2 = (const float*)d_in[5];
    const float* b2 = (const float*)d_in[6];
    float* out = (float*)d_out;

    char* ws = (char*)d_ws;
    unsigned int* packed = (unsigned int*)ws;                   ws += (size_t)N_NODES * 4;
    float* dinv    = (float*)ws;                                ws += (size_t)N_NODES * 4;
    int*   cnt     = (int*)ws;                                  ws += (size_t)N_NODES * 4;
    int*   row_ptr = (int*)ws;                                  ws += (size_t)(N_NODES + 1) * 4;
    int*   cursor  = (int*)ws;                                  ws += (size_t)N_NODES * 4;
    int*   bsum    = (int*)ws;                                  ws += (size_t)NBLK * 4;
    int2*  ebuf    = (int2*)ws;                                 ws += (size_t)N_EDGES * 8;
    unsigned short* hc = (unsigned short*)ws;                   ws += (size_t)N_NODES * HID * 2;
    unsigned short* wsw = (unsigned short*)ws;                  ws += (size_t)NF * HID * 2;
    float* agg     = (float*)ws;                                ws += (size_t)N_NODES * HID * 4;
    float* z       = (float*)ws;                                ws += (size_t)N_NODES * 4;

    hipMemsetAsync(packed, 0, N_NODES * 4, stream);

    degcnt_kernel<<<(N_EDGES + 255) / 256, 256, 0, stream>>>(ei, ew, packed);
    dinv_kernel<<<NBLK, 256, 0, stream>>>(packed, dinv, cnt, bsum);
    scanb_kernel<<<1, 512, 0, stream>>>(bsum);
    scan2_kernel<<<NBLK, 256, 0, stream>>>(cnt, bsum, row_ptr, cursor);
    scatter_kernel<<<(N_EDGES + 255) / 256, 256, 0, stream>>>(ei, ew, dinv, cursor, ebuf);

    wswiz_kernel<<<(NF * HID + 255) / 256, 256, 0, stream>>>(W1, wsw);
    gemm1_mfma<<<(N_NODES + 63) / 64, 256, 0, stream>>>(x, wsw, hc);

    int aggGrid = (N_NODES * 64 + 255) / 256;
    for (int p = 0; p < NPASS; ++p) {
        agg1_pass<<<aggGrid, 256, 0, stream>>>(row_ptr, ebuf,
                                               hc + (size_t)p * N_NODES * CHUNK, agg, p);
    }
    post1_kernel<<<aggGrid, 256, 0, stream>>>(agg, hc, dinv, b1, W2, z);
    fused2_kernel<<<aggGrid, 256, 0, stream>>>(row_ptr, ebuf, z, dinv, b2, out);
}

// Round 7
// 627.878 us; speedup vs baseline: 1.1994x; 1.1994x over previous
//
#include <hip/hip_runtime.h>

#define N_NODES 100000
#define N_EDGES 3200000
#define NF 256
#define HID 64
#define NBLK ((N_NODES + 255) / 256)   // 391 scan blocks

typedef short short8 __attribute__((ext_vector_type(8)));
typedef float f32x4 __attribute__((ext_vector_type(4)));

__device__ __forceinline__ unsigned short f2bf(float v) {
    unsigned int u = __float_as_uint(v);
    u += 0x7FFFu + ((u >> 16) & 1u);
    return (unsigned short)(u >> 16);
}

// ---------- single atomic pass: packed = cnt<<24 | fix16(ew-sum); rank[e] from old ----------
// max degree ~70 (Poisson(32)) << 255; sum(ew)*2^16 < 2^24.
__global__ void rank_kernel(const int* __restrict__ ei, const float* __restrict__ ew,
                            unsigned int* __restrict__ packed, unsigned int* __restrict__ rank) {
    int e = blockIdx.x * blockDim.x + threadIdx.x;
    if (e < N_EDGES) {
        int d = ei[N_EDGES + e];
        unsigned int fx = (unsigned int)(ew[e] * 65536.0f);
        unsigned int old = atomicAdd(&packed[d], (1u << 24) | fx);
        rank[e] = old >> 24;   // this edge's slot within dst row
    }
}

// dinv = rsqrt(deg + 1); unpack cnt; per-block sum of cnt -> bsum
__launch_bounds__(256)
__global__ void dinv_kernel(const unsigned int* __restrict__ packed,
                            float* __restrict__ dinv, int* __restrict__ cnt,
                            int* __restrict__ bsum) {
    __shared__ int sh[256];
    int t = threadIdx.x;
    int i = blockIdx.x * 256 + t;
    int c = 0;
    if (i < N_NODES) {
        unsigned int p = packed[i];
        float deg = (float)(p & 0xFFFFFFu) * (1.0f / 65536.0f);
        c = (int)(p >> 24);
        cnt[i] = c;
        dinv[i] = rsqrtf(deg + 1.0f);
    }
    sh[t] = c;
    __syncthreads();
    for (int off = 128; off > 0; off >>= 1) {
        if (t < off) sh[t] += sh[t + off];
        __syncthreads();
    }
    if (t == 0) bsum[blockIdx.x] = sh[0];
}

// ---------- exclusive scan of the 391 block sums (single tiny block) ----------
__launch_bounds__(512)
__global__ void scanb_kernel(int* __restrict__ bsum) {
    __shared__ int sh[512];
    int t = threadIdx.x;
    int v = (t < NBLK) ? bsum[t] : 0;
    sh[t] = v;
    __syncthreads();
    for (int off = 1; off < 512; off <<= 1) {
        int add = (t >= off) ? sh[t - off] : 0;
        __syncthreads();
        sh[t] += add;
        __syncthreads();
    }
    if (t < NBLK) bsum[t] = sh[t] - v;  // exclusive
}

// ---------- block-local scan + offset -> row_ptr ----------
__launch_bounds__(256)
__global__ void scan2_kernel(const int* __restrict__ cnt, const int* __restrict__ bsum,
                             int* __restrict__ row_ptr) {
    __shared__ int sh[256];
    int t = threadIdx.x;
    int i = blockIdx.x * 256 + t;
    int v = (i < N_NODES) ? cnt[i] : 0;
    sh[t] = v;
    __syncthreads();
    for (int off = 1; off < 256; off <<= 1) {
        int add = (t >= off) ? sh[t - off] : 0;
        __syncthreads();
        sh[t] += add;
        __syncthreads();
    }
    if (i < N_NODES) row_ptr[i] = bsum[blockIdx.x] + sh[t] - v;
    if (i == N_NODES - 1) row_ptr[N_NODES] = N_EDGES;
}

// ---------- atomic-free placement into CSR: 8B scattered writes only ----------
__global__ void place_kernel(const int* __restrict__ ei, const float* __restrict__ ew,
                             const unsigned int* __restrict__ rank,
                             const float* __restrict__ dinv, const int* __restrict__ row_ptr,
                             int2* __restrict__ ebuf) {
    int e = blockIdx.x * blockDim.x + threadIdx.x;
    if (e < N_EDGES) {
        int s = ei[e];
        int d = ei[N_EDGES + e];
        int pos = row_ptr[d] + (int)rank[e];
        float w = dinv[s] * ew[e] * dinv[d];
        ebuf[pos] = make_int2(s, __float_as_int(w));
    }
}

// ---------- one-time W1 swizzle into MFMA B-fragment order (bf16) ----------
__global__ void wswiz_kernel(const float* __restrict__ W, unsigned short* __restrict__ wsw) {
    int idx = blockIdx.x * blockDim.x + threadIdx.x;  // 0 .. 16383
    if (idx < NF * HID) {
        int j = idx & 7;
        int lane = (idx >> 3) & 63;
        int ntile = (idx >> 9) & 3;
        int kiter = idx >> 11;
        int k = kiter * 32 + (lane >> 4) * 8 + j;
        int n = ntile * 16 + (lane & 15);
        wsw[idx] = f2bf(W[k * HID + n]);
    }
}

// ---------- h = x @ W1 via MFMA (bf16 in, fp32 acc, bf16 out, row-major) ----------
__launch_bounds__(256)
__global__ void gemm1_mfma(const float* __restrict__ x, const unsigned short* __restrict__ wsw,
                           unsigned short* __restrict__ h) {
    int t = threadIdx.x;
    int lane = t & 63;
    int wave = t >> 6;
    int m = lane & 15;
    int quad = lane >> 4;
    int rowbase = blockIdx.x * 64 + wave * 16;

    int row = rowbase + m;
    if (row >= N_NODES) row = N_NODES - 1;

    const short8* wv = (const short8*)wsw;

    f32x4 acc[4] = {{0.f,0.f,0.f,0.f},{0.f,0.f,0.f,0.f},{0.f,0.f,0.f,0.f},{0.f,0.f,0.f,0.f}};

    const float* xrow = x + (size_t)row * NF;
#pragma unroll
    for (int kiter = 0; kiter < 8; ++kiter) {
        int k0 = kiter * 32 + quad * 8;
        float4 xa = *(const float4*)&xrow[k0];
        float4 xb = *(const float4*)&xrow[k0 + 4];
        short8 a;
        a[0] = (short)f2bf(xa.x); a[1] = (short)f2bf(xa.y);
        a[2] = (short)f2bf(xa.z); a[3] = (short)f2bf(xa.w);
        a[4] = (short)f2bf(xb.x); a[5] = (short)f2bf(xb.y);
        a[6] = (short)f2bf(xb.z); a[7] = (short)f2bf(xb.w);
#pragma unroll
        for (int nt = 0; nt < 4; ++nt) {
            short8 b = wv[(kiter * 4 + nt) * 64 + lane];
            acc[nt] = __builtin_amdgcn_mfma_f32_16x16x32_bf16(a, b, acc[nt], 0, 0, 0);
        }
    }

#pragma unroll
    for (int nt = 0; nt < 4; ++nt) {
#pragma unroll
        for (int r = 0; r < 4; ++r) {
            int orow = rowbase + quad * 4 + r;
            if (orow < N_NODES) {
                int ocol = nt * 16 + m;
                h[(size_t)orow * HID + ocol] = f2bf(acc[nt][r]);
            }
        }
    }
}

// ---------- fused layer-1 aggregation + self-loop + bias + ELU + @W2 ----------
// One wave per dst node; lane = feature. h is bf16 (128B gather per edge).
__launch_bounds__(256)
__global__ void fused1_kernel(const int* __restrict__ row_ptr, const int2* __restrict__ ebuf,
                              const unsigned short* __restrict__ h,
                              const float* __restrict__ dinv, const float* __restrict__ b1,
                              const float* __restrict__ W2, float* __restrict__ z) {
    int lane = threadIdx.x & 63;
    int d = (blockIdx.x * blockDim.x + threadIdx.x) >> 6;
    if (d >= N_NODES) return;

    int start = row_ptr[d];
    int end = row_ptr[d + 1];

    float acc = 0.0f;
    for (int base = start; base < end; base += 64) {
        int n = end - base; if (n > 64) n = 64;
        int idx = base + lane;
        int2 e = (lane < n) ? ebuf[idx] : make_int2(0, 0);
        for (int j = 0; j < n; ++j) {
            int s = __shfl(e.x, j);
            float w = __int_as_float(__shfl(e.y, j));
            float hv = __uint_as_float((unsigned int)h[(size_t)s * HID + lane] << 16);
            acc = fmaf(w, hv, acc);
        }
    }

    float di = dinv[d];
    float hd = __uint_as_float((unsigned int)h[(size_t)d * HID + lane] << 16);
    float v = acc + di * di * hd + b1[lane];
    v = (v > 0.0f) ? v : (__expf(v) - 1.0f);

    float p = v * W2[lane];
#pragma unroll
    for (int off = 32; off > 0; off >>= 1) p += __shfl_down(p, off);
    if (lane == 0) z[d] = p;
}

// ---------- fused layer-2 aggregation + self-loop + bias + sigmoid ----------
__launch_bounds__(256)
__global__ void fused2_kernel(const int* __restrict__ row_ptr, const int2* __restrict__ ebuf,
                              const float* __restrict__ z, const float* __restrict__ dinv,
                              const float* __restrict__ b2, float* __restrict__ out) {
    int lane = threadIdx.x & 63;
    int d = (blockIdx.x * blockDim.x + threadIdx.x) >> 6;
    if (d >= N_NODES) return;

    int start = row_ptr[d];
    int end = row_ptr[d + 1];

    float acc = 0.0f;
    for (int i = start + lane; i < end; i += 64) {
        int2 e = ebuf[i];
        acc = fmaf(__int_as_float(e.y), z[e.x], acc);
    }
#pragma unroll
    for (int off = 32; off > 0; off >>= 1) acc += __shfl_down(acc, off);

    if (lane == 0) {
        float di = dinv[d];
        float v = acc + di * di * z[d] + b2[0];
        out[d] = 1.0f / (1.0f + __expf(-v));
    }
}

extern "C" void kernel_launch(void* const* d_in, const int* in_sizes, int n_in,
                              void* d_out, int out_size, void* d_ws, size_t ws_size,
                              hipStream_t stream) {
    const float* x  = (const float*)d_in[0];
    const int*   ei = (const int*)d_in[1];
    const float* ew = (const float*)d_in[2];
    const float* W1 = (const float*)d_in[3];
    const float* b1 = (const float*)d_in[4];
    const float* W2 = (const float*)d_in[5];
    const float* b2 = (const float*)d_in[6];
    float* out = (float*)d_out;

    char* ws = (char*)d_ws;
    unsigned int* packed = (unsigned int*)ws;                   ws += (size_t)N_NODES * 4;
    float* dinv    = (float*)ws;                                ws += (size_t)N_NODES * 4;
    int*   cnt     = (int*)ws;                                  ws += (size_t)N_NODES * 4;
    int*   row_ptr = (int*)ws;                                  ws += (size_t)(N_NODES + 1) * 4;
    int*   bsum    = (int*)ws;                                  ws += (size_t)NBLK * 4;
    unsigned int* rank = (unsigned int*)ws;                     ws += (size_t)N_EDGES * 4;
    int2*  ebuf    = (int2*)ws;                                 ws += (size_t)N_EDGES * 8;
    unsigned short* h = (unsigned short*)ws;                    ws += (size_t)N_NODES * HID * 2;
    unsigned short* wsw = (unsigned short*)ws;                  ws += (size_t)NF * HID * 2;
    float* z       = (float*)ws;                                ws += (size_t)N_NODES * 4;

    hipMemsetAsync(packed, 0, N_NODES * 4, stream);

    rank_kernel<<<(N_EDGES + 255) / 256, 256, 0, stream>>>(ei, ew, packed, rank);
    dinv_kernel<<<NBLK, 256, 0, stream>>>(packed, dinv, cnt, bsum);
    scanb_kernel<<<1, 512, 0, stream>>>(bsum);
    scan2_kernel<<<NBLK, 256, 0, stream>>>(cnt, bsum, row_ptr);
    place_kernel<<<(N_EDGES + 255) / 256, 256, 0, stream>>>(ei, ew, rank, dinv, row_ptr, ebuf);

    wswiz_kernel<<<(NF * HID + 255) / 256, 256, 0, stream>>>(W1, wsw);
    gemm1_mfma<<<(N_NODES + 63) / 64, 256, 0, stream>>>(x, wsw, h);

    int grid = (N_NODES * 64 + 255) / 256;
    fused1_kernel<<<grid, 256, 0, stream>>>(row_ptr, ebuf, h, dinv, b1, W2, z);
    fused2_kernel<<<grid, 256, 0, stream>>>(row_ptr, ebuf, z, dinv, b2, out);
}

// Round 8
// 541.579 us; speedup vs baseline: 1.3905x; 1.1593x over previous
//
#include <hip/hip_runtime.h>

#define N_NODES 100000
#define N_EDGES 3200000
#define NF 256
#define HID 64
#define NBLK ((N_NODES + 255) / 256)   // 391 scan blocks

typedef short short8 __attribute__((ext_vector_type(8)));
typedef float f32x4 __attribute__((ext_vector_type(4)));

__device__ __forceinline__ unsigned short f2bf(float v) {
    unsigned int u = __float_as_uint(v);
    u += 0x7FFFu + ((u >> 16) & 1u);
    return (unsigned short)(u >> 16);
}
__device__ __forceinline__ float bfl(unsigned int p) {       // low bf16 -> f32
    return __uint_as_float((p & 0xFFFFu) << 16);
}
__device__ __forceinline__ float bfh(unsigned int p) {       // high bf16 -> f32
    return __uint_as_float(p & 0xFFFF0000u);
}

// ---------- single atomic pass: packed = cnt<<24 | fix16(ew-sum); rank[e] from old ----------
__global__ void rank_kernel(const int* __restrict__ ei, const float* __restrict__ ew,
                            unsigned int* __restrict__ packed, unsigned int* __restrict__ rank) {
    int e = blockIdx.x * blockDim.x + threadIdx.x;
    if (e < N_EDGES) {
        int d = ei[N_EDGES + e];
        unsigned int fx = (unsigned int)(ew[e] * 65536.0f);
        unsigned int old = atomicAdd(&packed[d], (1u << 24) | fx);
        rank[e] = old >> 24;
    }
}

// dinv = rsqrt(deg + 1); unpack cnt; per-block sum of cnt -> bsum
__launch_bounds__(256)
__global__ void dinv_kernel(const unsigned int* __restrict__ packed,
                            float* __restrict__ dinv, int* __restrict__ cnt,
                            int* __restrict__ bsum) {
    __shared__ int sh[256];
    int t = threadIdx.x;
    int i = blockIdx.x * 256 + t;
    int c = 0;
    if (i < N_NODES) {
        unsigned int p = packed[i];
        float deg = (float)(p & 0xFFFFFFu) * (1.0f / 65536.0f);
        c = (int)(p >> 24);
        cnt[i] = c;
        dinv[i] = rsqrtf(deg + 1.0f);
    }
    sh[t] = c;
    __syncthreads();
    for (int off = 128; off > 0; off >>= 1) {
        if (t < off) sh[t] += sh[t + off];
        __syncthreads();
    }
    if (t == 0) bsum[blockIdx.x] = sh[0];
}

// ---------- exclusive scan of the 391 block sums (single tiny block) ----------
__launch_bounds__(512)
__global__ void scanb_kernel(int* __restrict__ bsum) {
    __shared__ int sh[512];
    int t = threadIdx.x;
    int v = (t < NBLK) ? bsum[t] : 0;
    sh[t] = v;
    __syncthreads();
    for (int off = 1; off < 512; off <<= 1) {
        int add = (t >= off) ? sh[t - off] : 0;
        __syncthreads();
        sh[t] += add;
        __syncthreads();
    }
    if (t < NBLK) bsum[t] = sh[t] - v;  // exclusive
}

// ---------- block-local scan + offset -> row_ptr ----------
__launch_bounds__(256)
__global__ void scan2_kernel(const int* __restrict__ cnt, const int* __restrict__ bsum,
                             int* __restrict__ row_ptr) {
    __shared__ int sh[256];
    int t = threadIdx.x;
    int i = blockIdx.x * 256 + t;
    int v = (i < N_NODES) ? cnt[i] : 0;
    sh[t] = v;
    __syncthreads();
    for (int off = 1; off < 256; off <<= 1) {
        int add = (t >= off) ? sh[t - off] : 0;
        __syncthreads();
        sh[t] += add;
        __syncthreads();
    }
    if (i < N_NODES) row_ptr[i] = bsum[blockIdx.x] + sh[t] - v;
    if (i == N_NODES - 1) row_ptr[N_NODES] = N_EDGES;
}

// ---------- atomic-free placement into CSR: 8B scattered writes only ----------
__global__ void place_kernel(const int* __restrict__ ei, const float* __restrict__ ew,
                             const unsigned int* __restrict__ rank,
                             const float* __restrict__ dinv, const int* __restrict__ row_ptr,
                             int2* __restrict__ ebuf) {
    int e = blockIdx.x * blockDim.x + threadIdx.x;
    if (e < N_EDGES) {
        int s = ei[e];
        int d = ei[N_EDGES + e];
        int pos = row_ptr[d] + (int)rank[e];
        float w = dinv[s] * ew[e] * dinv[d];
        ebuf[pos] = make_int2(s, __float_as_int(w));
    }
}

// ---------- one-time W1 swizzle into MFMA B-fragment order (bf16) ----------
__global__ void wswiz_kernel(const float* __restrict__ W, unsigned short* __restrict__ wsw) {
    int idx = blockIdx.x * blockDim.x + threadIdx.x;  // 0 .. 16383
    if (idx < NF * HID) {
        int j = idx & 7;
        int lane = (idx >> 3) & 63;
        int ntile = (idx >> 9) & 3;
        int kiter = idx >> 11;
        int k = kiter * 32 + (lane >> 4) * 8 + j;
        int n = ntile * 16 + (lane & 15);
        wsw[idx] = f2bf(W[k * HID + n]);
    }
}

// ---------- h = x @ W1 via MFMA (bf16 in, fp32 acc, bf16 out, row-major) ----------
__launch_bounds__(256)
__global__ void gemm1_mfma(const float* __restrict__ x, const unsigned short* __restrict__ wsw,
                           unsigned short* __restrict__ h) {
    int t = threadIdx.x;
    int lane = t & 63;
    int wave = t >> 6;
    int m = lane & 15;
    int quad = lane >> 4;
    int rowbase = blockIdx.x * 64 + wave * 16;

    int row = rowbase + m;
    if (row >= N_NODES) row = N_NODES - 1;

    const short8* wv = (const short8*)wsw;

    f32x4 acc[4] = {{0.f,0.f,0.f,0.f},{0.f,0.f,0.f,0.f},{0.f,0.f,0.f,0.f},{0.f,0.f,0.f,0.f}};

    const float* xrow = x + (size_t)row * NF;
#pragma unroll
    for (int kiter = 0; kiter < 8; ++kiter) {
        int k0 = kiter * 32 + quad * 8;
        float4 xa = *(const float4*)&xrow[k0];
        float4 xb = *(const float4*)&xrow[k0 + 4];
        short8 a;
        a[0] = (short)f2bf(xa.x); a[1] = (short)f2bf(xa.y);
        a[2] = (short)f2bf(xa.z); a[3] = (short)f2bf(xa.w);
        a[4] = (short)f2bf(xb.x); a[5] = (short)f2bf(xb.y);
        a[6] = (short)f2bf(xb.z); a[7] = (short)f2bf(xb.w);
#pragma unroll
        for (int nt = 0; nt < 4; ++nt) {
            short8 b = wv[(kiter * 4 + nt) * 64 + lane];
            acc[nt] = __builtin_amdgcn_mfma_f32_16x16x32_bf16(a, b, acc[nt], 0, 0, 0);
        }
    }

#pragma unroll
    for (int nt = 0; nt < 4; ++nt) {
#pragma unroll
        for (int r = 0; r < 4; ++r) {
            int orow = rowbase + quad * 4 + r;
            if (orow < N_NODES) {
                int ocol = nt * 16 + m;
                h[(size_t)orow * HID + ocol] = f2bf(acc[nt][r]);
            }
        }
    }
}

// ---------- fused layer-1 aggregation + self-loop + bias + ELU + @W2 ----------
// One wave per dst. Lanes = 4 edge-groups x 16 feature-quads: each lane loads
// uint2 (4 bf16 features), so one wave instruction gathers 4 edge rows (512B);
// unrolled x4 => ~16 edges / 4 gathers in flight per wave (MLP, not locality).
__launch_bounds__(256)
__global__ void fused1_kernel(const int* __restrict__ row_ptr, const int2* __restrict__ ebuf,
                              const unsigned short* __restrict__ h,
                              const float* __restrict__ dinv, const float* __restrict__ b1,
                              const float* __restrict__ W2, float* __restrict__ z) {
    int lane = threadIdx.x & 63;
    int d = (blockIdx.x * blockDim.x + threadIdx.x) >> 6;
    if (d >= N_NODES) return;

    int start = row_ptr[d];
    int end = row_ptr[d + 1];
    int f = lane & 15;   // feature-quad: features 4f..4f+3
    int g = lane >> 4;   // edge-group 0..3

    const uint2* h64 = (const uint2*)h;   // one row = 16 uint2

    float4 acc = make_float4(0.f, 0.f, 0.f, 0.f);

    for (int base = start; base < end; base += 64) {
        int n = end - base; if (n > 64) n = 64;
        int2 e = (lane < n) ? ebuf[base + lane] : make_int2(0, 0);
        int j = 0;
        for (; j + 16 <= n; j += 16) {
            uint2 hp[4]; float w[4];
#pragma unroll
            for (int u = 0; u < 4; ++u) {
                int idx = j + u * 4 + g;
                int s = __shfl(e.x, idx);
                w[u] = __int_as_float(__shfl(e.y, idx));
                hp[u] = h64[(size_t)s * 16 + f];
            }
#pragma unroll
            for (int u = 0; u < 4; ++u) {
                acc.x = fmaf(w[u], bfl(hp[u].x), acc.x);
                acc.y = fmaf(w[u], bfh(hp[u].x), acc.y);
                acc.z = fmaf(w[u], bfl(hp[u].y), acc.z);
                acc.w = fmaf(w[u], bfh(hp[u].y), acc.w);
            }
        }
        for (; j + 4 <= n; j += 4) {
            int idx = j + g;
            int s = __shfl(e.x, idx);
            float w = __int_as_float(__shfl(e.y, idx));
            uint2 hp = h64[(size_t)s * 16 + f];
            acc.x = fmaf(w, bfl(hp.x), acc.x);
            acc.y = fmaf(w, bfh(hp.x), acc.y);
            acc.z = fmaf(w, bfl(hp.y), acc.z);
            acc.w = fmaf(w, bfh(hp.y), acc.w);
        }
        int rem = n - j;  // 0..3
        if (rem > 0) {
            int idx = j + (g < rem ? g : 0);
            int s = __shfl(e.x, idx);
            float w = __int_as_float(__shfl(e.y, idx));
            if (g < rem) {
                uint2 hp = h64[(size_t)s * 16 + f];
                acc.x = fmaf(w, bfl(hp.x), acc.x);
                acc.y = fmaf(w, bfh(hp.x), acc.y);
                acc.z = fmaf(w, bfl(hp.y), acc.z);
                acc.w = fmaf(w, bfh(hp.y), acc.w);
            }
        }
    }

    // reduce the 4 edge-groups: lanes 0..15 end with the full sums
    acc.x += __shfl_down(acc.x, 32); acc.y += __shfl_down(acc.y, 32);
    acc.z += __shfl_down(acc.z, 32); acc.w += __shfl_down(acc.w, 32);
    acc.x += __shfl_down(acc.x, 16); acc.y += __shfl_down(acc.y, 16);
    acc.z += __shfl_down(acc.z, 16); acc.w += __shfl_down(acc.w, 16);

    // epilogue (valid on lanes 0..15; harmless elsewhere)
    float di = dinv[d];
    float d2 = di * di;
    uint2 hd = h64[(size_t)d * 16 + f];
    float4 b = *(const float4*)&b1[4 * f];
    float4 w2 = *(const float4*)&W2[4 * f];

    float v0 = acc.x + d2 * bfl(hd.x) + b.x;
    float v1 = acc.y + d2 * bfh(hd.x) + b.y;
    float v2 = acc.z + d2 * bfl(hd.y) + b.z;
    float v3 = acc.w + d2 * bfh(hd.y) + b.w;
    v0 = (v0 > 0.f) ? v0 : (__expf(v0) - 1.f);
    v1 = (v1 > 0.f) ? v1 : (__expf(v1) - 1.f);
    v2 = (v2 > 0.f) ? v2 : (__expf(v2) - 1.f);
    v3 = (v3 > 0.f) ? v3 : (__expf(v3) - 1.f);

    float p = v0 * w2.x + v1 * w2.y + v2 * w2.z + v3 * w2.w;
    p += __shfl_down(p, 8);
    p += __shfl_down(p, 4);
    p += __shfl_down(p, 2);
    p += __shfl_down(p, 1);
    if (lane == 0) z[d] = p;
}

// ---------- fused layer-2 aggregation + self-loop + bias + sigmoid ----------
__launch_bounds__(256)
__global__ void fused2_kernel(const int* __restrict__ row_ptr, const int2* __restrict__ ebuf,
                              const float* __restrict__ z, const float* __restrict__ dinv,
                              const float* __restrict__ b2, float* __restrict__ out) {
    int lane = threadIdx.x & 63;
    int d = (blockIdx.x * blockDim.x + threadIdx.x) >> 6;
    if (d >= N_NODES) return;

    int start = row_ptr[d];
    int end = row_ptr[d + 1];

    float acc = 0.0f;
    for (int i = start + lane; i < end; i += 64) {
        int2 e = ebuf[i];
        acc = fmaf(__int_as_float(e.y), z[e.x], acc);
    }
#pragma unroll
    for (int off = 32; off > 0; off >>= 1) acc += __shfl_down(acc, off);

    if (lane == 0) {
        float di = dinv[d];
        float v = acc + di * di * z[d] + b2[0];
        out[d] = 1.0f / (1.0f + __expf(-v));
    }
}

extern "C" void kernel_launch(void* const* d_in, const int* in_sizes, int n_in,
                              void* d_out, int out_size, void* d_ws, size_t ws_size,
                              hipStream_t stream) {
    const float* x  = (const float*)d_in[0];
    const int*   ei = (const int*)d_in[1];
    const float* ew = (const float*)d_in[2];
    const float* W1 = (const float*)d_in[3];
    const float* b1 = (const float*)d_in[4];
    const float* W2 = (const float*)d_in[5];
    const float* b2 = (const float*)d_in[6];
    float* out = (float*)d_out;

    char* ws = (char*)d_ws;
    unsigned int* packed = (unsigned int*)ws;                   ws += (size_t)N_NODES * 4;
    float* dinv    = (float*)ws;                                ws += (size_t)N_NODES * 4;
    int*   cnt     = (int*)ws;                                  ws += (size_t)N_NODES * 4;
    int*   row_ptr = (int*)ws;                                  ws += (size_t)(N_NODES + 1) * 4;
    int*   bsum    = (int*)ws;                                  ws += (size_t)NBLK * 4;
    unsigned int* rank = (unsigned int*)ws;                     ws += (size_t)N_EDGES * 4;
    int2*  ebuf    = (int2*)ws;                                 ws += (size_t)N_EDGES * 8;
    unsigned short* h = (unsigned short*)ws;                    ws += (size_t)N_NODES * HID * 2;
    unsigned short* wsw = (unsigned short*)ws;                  ws += (size_t)NF * HID * 2;
    float* z       = (float*)ws;                                ws += (size_t)N_NODES * 4;

    hipMemsetAsync(packed, 0, N_NODES * 4, stream);

    rank_kernel<<<(N_EDGES + 255) / 256, 256, 0, stream>>>(ei, ew, packed, rank);
    dinv_kernel<<<NBLK, 256, 0, stream>>>(packed, dinv, cnt, bsum);
    scanb_kernel<<<1, 512, 0, stream>>>(bsum);
    scan2_kernel<<<NBLK, 256, 0, stream>>>(cnt, bsum, row_ptr);
    place_kernel<<<(N_EDGES + 255) / 256, 256, 0, stream>>>(ei, ew, rank, dinv, row_ptr, ebuf);

    wswiz_kernel<<<(NF * HID + 255) / 256, 256, 0, stream>>>(W1, wsw);
    gemm1_mfma<<<(N_NODES + 63) / 64, 256, 0, stream>>>(x, wsw, h);

    int grid = (N_NODES * 64 + 255) / 256;
    fused1_kernel<<<grid, 256, 0, stream>>>(row_ptr, ebuf, h, dinv, b1, W2, z);
    fused2_kernel<<<grid, 256, 0, stream>>>(row_ptr, ebuf, z, dinv, b2, out);
}

// Round 9
// 539.229 us; speedup vs baseline: 1.3966x; 1.0044x over previous
//
#include <hip/hip_runtime.h>

#define N_NODES 100000
#define N_EDGES 3200000
#define NF 256
#define HID 64
#define BSHIFT 7
#define NBUCK 782                       // ceil(100000 / 128)
#define NP1 128                         // phase-1 partition blocks
#define CHUNKE ((N_EDGES + NP1 - 1) / NP1)

typedef short short8 __attribute__((ext_vector_type(8)));
typedef float f32x4 __attribute__((ext_vector_type(4)));

__device__ __forceinline__ unsigned short f2bf(float v) {
    unsigned int u = __float_as_uint(v);
    u += 0x7FFFu + ((u >> 16) & 1u);
    return (unsigned short)(u >> 16);
}
__device__ __forceinline__ float bfl(unsigned int p) { return __uint_as_float((p & 0xFFFFu) << 16); }
__device__ __forceinline__ float bfh(unsigned int p) { return __uint_as_float(p & 0xFFFF0000u); }

// ---------- phase 1a: per-block LDS histogram of dst buckets ----------
__launch_bounds__(256)
__global__ void p1count(const int* __restrict__ ei, unsigned int* __restrict__ bucket_total) {
    __shared__ unsigned int hist[NBUCK];
    for (int i = threadIdx.x; i < NBUCK; i += 256) hist[i] = 0;
    __syncthreads();
    int lo = blockIdx.x * CHUNKE;
    int hi = lo + CHUNKE; if (hi > N_EDGES) hi = N_EDGES;
    for (int e = lo + threadIdx.x; e < hi; e += 256)
        atomicAdd(&hist[((unsigned)ei[N_EDGES + e]) >> BSHIFT], 1u);
    __syncthreads();
    for (int i = threadIdx.x; i < NBUCK; i += 256) {
        unsigned c = hist[i];
        if (c) atomicAdd(&bucket_total[i], c);
    }
}

// ---------- phase 1b: scan bucket totals -> base, cursor ----------
__launch_bounds__(1024)
__global__ void scanbkt(const unsigned int* __restrict__ bucket_total,
                        unsigned int* __restrict__ base, unsigned int* __restrict__ cursor) {
    __shared__ unsigned int sh[1024];
    int t = threadIdx.x;
    unsigned v = (t < NBUCK) ? bucket_total[t] : 0;
    sh[t] = v;
    __syncthreads();
    for (int off = 1; off < 1024; off <<= 1) {
        unsigned a = (t >= off) ? sh[t - off] : 0;
        __syncthreads();
        sh[t] += a;
        __syncthreads();
    }
    if (t < NBUCK) { unsigned ex = sh[t] - v; base[t] = ex; cursor[t] = ex; }
    if (t == 0) base[NBUCK] = N_EDGES;
}

// ---------- phase 1c: partition edges into buckets (LDS ranks, ~1 atomic per block-bucket) ----------
// pbuf entry: x = src | (dst_low7 << 17), y = ew bits
__launch_bounds__(256)
__global__ void p1scatter(const int* __restrict__ ei, const float* __restrict__ ew,
                          unsigned int* __restrict__ cursor, int2* __restrict__ pbuf) {
    __shared__ unsigned int hist[NBUCK];
    __shared__ unsigned int bas[NBUCK];
    for (int i = threadIdx.x; i < NBUCK; i += 256) hist[i] = 0;
    __syncthreads();
    int lo = blockIdx.x * CHUNKE;
    int hi = lo + CHUNKE; if (hi > N_EDGES) hi = N_EDGES;
    for (int e = lo + threadIdx.x; e < hi; e += 256)
        atomicAdd(&hist[((unsigned)ei[N_EDGES + e]) >> BSHIFT], 1u);
    __syncthreads();
    for (int i = threadIdx.x; i < NBUCK; i += 256) {
        unsigned c = hist[i];
        bas[i] = c ? atomicAdd(&cursor[i], c) : 0u;
        hist[i] = 0;   // reuse as local cursor
    }
    __syncthreads();
    for (int e = lo + threadIdx.x; e < hi; e += 256) {
        int s = ei[e];
        unsigned d = (unsigned)ei[N_EDGES + e];
        unsigned bkt = d >> BSHIFT;
        unsigned loc = atomicAdd(&hist[bkt], 1u);
        pbuf[bas[bkt] + loc] = make_int2(s | (int)((d & 127u) << 17), __float_as_int(ew[e]));
    }
}

// ---------- phase 2a: per-bucket cnt + weighted degree via LDS ----------
__launch_bounds__(256)
__global__ void p2a(const int2* __restrict__ pbuf, const unsigned int* __restrict__ base,
                    int* __restrict__ cnt, float* __restrict__ deg) {
    __shared__ int lc[128];
    __shared__ float ld[128];
    int t = threadIdx.x;
    if (t < 128) { lc[t] = 0; ld[t] = 0.f; }
    __syncthreads();
    unsigned lo = base[blockIdx.x], hi = base[blockIdx.x + 1];
    for (unsigned i = lo + t; i < hi; i += 256) {
        int2 e = pbuf[i];
        int dl = (e.x >> 17) & 127;
        atomicAdd(&lc[dl], 1);
        atomicAdd(&ld[dl], __int_as_float(e.y));
    }
    __syncthreads();
    int d0 = blockIdx.x << BSHIFT;
    if (t < 128 && d0 + t < N_NODES) { cnt[d0 + t] = lc[t]; deg[d0 + t] = ld[t]; }
}

// ---------- dinv = rsqrt(deg + 1) ----------
__global__ void dinv_kernel(const float* __restrict__ deg, float* __restrict__ dinv) {
    int i = blockIdx.x * blockDim.x + threadIdx.x;
    if (i < N_NODES) dinv[i] = rsqrtf(deg[i] + 1.0f);
}

// ---------- phase 2b: row_ptr + final CSR with normalized weights ----------
__launch_bounds__(256)
__global__ void p2b(const int2* __restrict__ pbuf, const unsigned int* __restrict__ base,
                    const int* __restrict__ cnt, const float* __restrict__ dinv,
                    int* __restrict__ row_ptr, int2* __restrict__ ebuf) {
    __shared__ int sc[128];
    __shared__ int loff[128];
    __shared__ unsigned int lcur[128];
    int t = threadIdx.x;
    int d0 = blockIdx.x << BSHIFT;
    int nd = N_NODES - d0; if (nd > 128) nd = 128;

    int c = (t < 128 && t < nd) ? cnt[d0 + t] : 0;
    if (t < 128) sc[t] = c;
    __syncthreads();
    for (int off = 1; off < 128; off <<= 1) {
        int a = (t < 128 && t >= off) ? sc[t - off] : 0;
        __syncthreads();
        if (t < 128) sc[t] += a;
        __syncthreads();
    }
    unsigned b0 = base[blockIdx.x];
    if (t < 128) {
        int excl = sc[t] - c;
        loff[t] = excl;
        lcur[t] = 0;
        if (t < nd) row_ptr[d0 + t] = (int)(b0 + excl);
    }
    if (blockIdx.x == NBUCK - 1 && t == 0) row_ptr[N_NODES] = N_EDGES;
    __syncthreads();

    unsigned hi = base[blockIdx.x + 1];
    for (unsigned i = b0 + t; i < hi; i += 256) {
        int2 e = pbuf[i];
        int s = e.x & 0x1FFFF;
        int dl = (e.x >> 17) & 127;
        unsigned r = atomicAdd(&lcur[dl], 1u);
        float w = dinv[s] * __int_as_float(e.y) * dinv[d0 + dl];
        ebuf[b0 + loff[dl] + r] = make_int2(s, __float_as_int(w));
    }
}

// ---------- one-time W1 swizzle into MFMA B-fragment order (bf16) ----------
__global__ void wswiz_kernel(const float* __restrict__ W, unsigned short* __restrict__ wsw) {
    int idx = blockIdx.x * blockDim.x + threadIdx.x;  // 0 .. 16383
    if (idx < NF * HID) {
        int j = idx & 7;
        int lane = (idx >> 3) & 63;
        int ntile = (idx >> 9) & 3;
        int kiter = idx >> 11;
        int k = kiter * 32 + (lane >> 4) * 8 + j;
        int n = ntile * 16 + (lane & 15);
        wsw[idx] = f2bf(W[k * HID + n]);
    }
}

// ---------- h = x @ W1 via MFMA (bf16 in, fp32 acc, bf16 out, row-major) ----------
__launch_bounds__(256)
__global__ void gemm1_mfma(const float* __restrict__ x, const unsigned short* __restrict__ wsw,
                           unsigned short* __restrict__ h) {
    int t = threadIdx.x;
    int lane = t & 63;
    int wave = t >> 6;
    int m = lane & 15;
    int quad = lane >> 4;
    int rowbase = blockIdx.x * 64 + wave * 16;

    int row = rowbase + m;
    if (row >= N_NODES) row = N_NODES - 1;

    const short8* wv = (const short8*)wsw;

    f32x4 acc[4] = {{0.f,0.f,0.f,0.f},{0.f,0.f,0.f,0.f},{0.f,0.f,0.f,0.f},{0.f,0.f,0.f,0.f}};

    const float* xrow = x + (size_t)row * NF;
#pragma unroll
    for (int kiter = 0; kiter < 8; ++kiter) {
        int k0 = kiter * 32 + quad * 8;
        float4 xa = *(const float4*)&xrow[k0];
        float4 xb = *(const float4*)&xrow[k0 + 4];
        short8 a;
        a[0] = (short)f2bf(xa.x); a[1] = (short)f2bf(xa.y);
        a[2] = (short)f2bf(xa.z); a[3] = (short)f2bf(xa.w);
        a[4] = (short)f2bf(xb.x); a[5] = (short)f2bf(xb.y);
        a[6] = (short)f2bf(xb.z); a[7] = (short)f2bf(xb.w);
#pragma unroll
        for (int nt = 0; nt < 4; ++nt) {
            short8 b = wv[(kiter * 4 + nt) * 64 + lane];
            acc[nt] = __builtin_amdgcn_mfma_f32_16x16x32_bf16(a, b, acc[nt], 0, 0, 0);
        }
    }

#pragma unroll
    for (int nt = 0; nt < 4; ++nt) {
#pragma unroll
        for (int r = 0; r < 4; ++r) {
            int orow = rowbase + quad * 4 + r;
            if (orow < N_NODES) {
                int ocol = nt * 16 + m;
                h[(size_t)orow * HID + ocol] = f2bf(acc[nt][r]);
            }
        }
    }
}

// ---------- fused layer-1 aggregation + self-loop + bias + ELU + @W2 ----------
// One wave per dst. Lanes = 4 edge-groups x 16 feature-quads; each lane loads
// uint2 (4 bf16); one wave instruction gathers 4 edge rows; unrolled x4.
__launch_bounds__(256)
__global__ void fused1_kernel(const int* __restrict__ row_ptr, const int2* __restrict__ ebuf,
                              const unsigned short* __restrict__ h,
                              const float* __restrict__ dinv, const float* __restrict__ b1,
                              const float* __restrict__ W2, float* __restrict__ z) {
    int lane = threadIdx.x & 63;
    int d = (blockIdx.x * blockDim.x + threadIdx.x) >> 6;
    if (d >= N_NODES) return;

    int start = row_ptr[d];
    int end = row_ptr[d + 1];
    int f = lane & 15;
    int g = lane >> 4;

    const uint2* h64 = (const uint2*)h;

    float4 acc = make_float4(0.f, 0.f, 0.f, 0.f);

    for (int base = start; base < end; base += 64) {
        int n = end - base; if (n > 64) n = 64;
        int2 e = (lane < n) ? ebuf[base + lane] : make_int2(0, 0);
        int j = 0;
        for (; j + 16 <= n; j += 16) {
            uint2 hp[4]; float w[4];
#pragma unroll
            for (int u = 0; u < 4; ++u) {
                int idx = j + u * 4 + g;
                int s = __shfl(e.x, idx);
                w[u] = __int_as_float(__shfl(e.y, idx));
                hp[u] = h64[(size_t)s * 16 + f];
            }
#pragma unroll
            for (int u = 0; u < 4; ++u) {
                acc.x = fmaf(w[u], bfl(hp[u].x), acc.x);
                acc.y = fmaf(w[u], bfh(hp[u].x), acc.y);
                acc.z = fmaf(w[u], bfl(hp[u].y), acc.z);
                acc.w = fmaf(w[u], bfh(hp[u].y), acc.w);
            }
        }
        for (; j + 4 <= n; j += 4) {
            int idx = j + g;
            int s = __shfl(e.x, idx);
            float w = __int_as_float(__shfl(e.y, idx));
            uint2 hp = h64[(size_t)s * 16 + f];
            acc.x = fmaf(w, bfl(hp.x), acc.x);
            acc.y = fmaf(w, bfh(hp.x), acc.y);
            acc.z = fmaf(w, bfl(hp.y), acc.z);
            acc.w = fmaf(w, bfh(hp.y), acc.w);
        }
        int rem = n - j;
        if (rem > 0) {
            int idx = j + (g < rem ? g : 0);
            int s = __shfl(e.x, idx);
            float w = __int_as_float(__shfl(e.y, idx));
            if (g < rem) {
                uint2 hp = h64[(size_t)s * 16 + f];
                acc.x = fmaf(w, bfl(hp.x), acc.x);
                acc.y = fmaf(w, bfh(hp.x), acc.y);
                acc.z = fmaf(w, bfl(hp.y), acc.z);
                acc.w = fmaf(w, bfh(hp.y), acc.w);
            }
        }
    }

    acc.x += __shfl_down(acc.x, 32); acc.y += __shfl_down(acc.y, 32);
    acc.z += __shfl_down(acc.z, 32); acc.w += __shfl_down(acc.w, 32);
    acc.x += __shfl_down(acc.x, 16); acc.y += __shfl_down(acc.y, 16);
    acc.z += __shfl_down(acc.z, 16); acc.w += __shfl_down(acc.w, 16);

    float di = dinv[d];
    float d2 = di * di;
    uint2 hd = h64[(size_t)d * 16 + f];
    float4 b = *(const float4*)&b1[4 * f];
    float4 w2 = *(const float4*)&W2[4 * f];

    float v0 = acc.x + d2 * bfl(hd.x) + b.x;
    float v1 = acc.y + d2 * bfh(hd.x) + b.y;
    float v2 = acc.z + d2 * bfl(hd.y) + b.z;
    float v3 = acc.w + d2 * bfh(hd.y) + b.w;
    v0 = (v0 > 0.f) ? v0 : (__expf(v0) - 1.f);
    v1 = (v1 > 0.f) ? v1 : (__expf(v1) - 1.f);
    v2 = (v2 > 0.f) ? v2 : (__expf(v2) - 1.f);
    v3 = (v3 > 0.f) ? v3 : (__expf(v3) - 1.f);

    float p = v0 * w2.x + v1 * w2.y + v2 * w2.z + v3 * w2.w;
    p += __shfl_down(p, 8);
    p += __shfl_down(p, 4);
    p += __shfl_down(p, 2);
    p += __shfl_down(p, 1);
    if (lane == 0) z[d] = p;
}

// ---------- fused layer-2 aggregation + self-loop + bias + sigmoid ----------
__launch_bounds__(256)
__global__ void fused2_kernel(const int* __restrict__ row_ptr, const int2* __restrict__ ebuf,
                              const float* __restrict__ z, const float* __restrict__ dinv,
                              const float* __restrict__ b2, float* __restrict__ out) {
    int lane = threadIdx.x & 63;
    int d = (blockIdx.x * blockDim.x + threadIdx.x) >> 6;
    if (d >= N_NODES) return;

    int start = row_ptr[d];
    int end = row_ptr[d + 1];

    float acc = 0.0f;
    for (int i = start + lane; i < end; i += 64) {
        int2 e = ebuf[i];
        acc = fmaf(__int_as_float(e.y), z[e.x], acc);
    }
#pragma unroll
    for (int off = 32; off > 0; off >>= 1) acc += __shfl_down(acc, off);

    if (lane == 0) {
        float di = dinv[d];
        float v = acc + di * di * z[d] + b2[0];
        out[d] = 1.0f / (1.0f + __expf(-v));
    }
}

extern "C" void kernel_launch(void* const* d_in, const int* in_sizes, int n_in,
                              void* d_out, int out_size, void* d_ws, size_t ws_size,
                              hipStream_t stream) {
    const float* x  = (const float*)d_in[0];
    const int*   ei = (const int*)d_in[1];
    const float* ew = (const float*)d_in[2];
    const float* W1 = (const float*)d_in[3];
    const float* b1 = (const float*)d_in[4];
    const float* W2 = (const float*)d_in[5];
    const float* b2 = (const float*)d_in[6];
    float* out = (float*)d_out;

    char* ws = (char*)d_ws;
    unsigned int* bucket_total = (unsigned int*)ws;             ws += (size_t)NBUCK * 4;
    unsigned int* base   = (unsigned int*)ws;                   ws += (size_t)(NBUCK + 1) * 4;
    unsigned int* cursor = (unsigned int*)ws;                   ws += (size_t)NBUCK * 4;
    int*   cnt     = (int*)ws;                                  ws += (size_t)N_NODES * 4;
    float* deg     = (float*)ws;                                ws += (size_t)N_NODES * 4;
    float* dinv    = (float*)ws;                                ws += (size_t)N_NODES * 4;
    int*   row_ptr = (int*)ws;                                  ws += (size_t)(N_NODES + 1) * 4;
    int2*  pbuf    = (int2*)ws;                                 ws += (size_t)N_EDGES * 8;
    int2*  ebuf    = (int2*)ws;                                 ws += (size_t)N_EDGES * 8;
    unsigned short* h = (unsigned short*)ws;                    ws += (size_t)N_NODES * HID * 2;
    unsigned short* wsw = (unsigned short*)ws;                  ws += (size_t)NF * HID * 2;
    float* z       = (float*)ws;                                ws += (size_t)N_NODES * 4;

    hipMemsetAsync(bucket_total, 0, NBUCK * 4, stream);

    p1count<<<NP1, 256, 0, stream>>>(ei, bucket_total);
    scanbkt<<<1, 1024, 0, stream>>>(bucket_total, base, cursor);
    p1scatter<<<NP1, 256, 0, stream>>>(ei, ew, cursor, pbuf);
    p2a<<<NBUCK, 256, 0, stream>>>(pbuf, base, cnt, deg);
    dinv_kernel<<<(N_NODES + 255) / 256, 256, 0, stream>>>(deg, dinv);
    p2b<<<NBUCK, 256, 0, stream>>>(pbuf, base, cnt, dinv, row_ptr, ebuf);

    wswiz_kernel<<<(NF * HID + 255) / 256, 256, 0, stream>>>(W1, wsw);
    gemm1_mfma<<<(N_NODES + 63) / 64, 256, 0, stream>>>(x, wsw, h);

    int grid = (N_NODES * 64 + 255) / 256;
    fused1_kernel<<<grid, 256, 0, stream>>>(row_ptr, ebuf, h, dinv, b1, W2, z);
    fused2_kernel<<<grid, 256, 0, stream>>>(row_ptr, ebuf, z, dinv, b2, out);
}

// Round 10
// 463.786 us; speedup vs baseline: 1.6237x; 1.1627x over previous
//
#include <hip/hip_runtime.h>

#define N_NODES 100000
#define N_EDGES 3200000
#define NF 256
#define HID 64
#define BSHIFT 7
#define NBUCK 782                       // ceil(100000 / 128)
#define NP1 1024                        // phase-1 partition blocks
#define CHUNKE ((N_EDGES + NP1 - 1) / NP1)   // 3125

typedef short short8 __attribute__((ext_vector_type(8)));
typedef float f32x4 __attribute__((ext_vector_type(4)));

__device__ __forceinline__ unsigned short f2bf(float v) {
    unsigned int u = __float_as_uint(v);
    u += 0x7FFFu + ((u >> 16) & 1u);
    return (unsigned short)(u >> 16);
}
__device__ __forceinline__ float bfl(unsigned int p) { return __uint_as_float((p & 0xFFFFu) << 16); }
__device__ __forceinline__ float bfh(unsigned int p) { return __uint_as_float(p & 0xFFFF0000u); }

// ---------- 1a: per-block LDS histogram -> blkhist[block][bucket] (coalesced row) ----------
__launch_bounds__(256)
__global__ void p1count(const int* __restrict__ ei, unsigned int* __restrict__ blkhist) {
    __shared__ unsigned int hist[NBUCK];
    for (int i = threadIdx.x; i < NBUCK; i += 256) hist[i] = 0;
    __syncthreads();
    int lo = blockIdx.x * CHUNKE;
    int hi = lo + CHUNKE; if (hi > N_EDGES) hi = N_EDGES;
    for (int e = lo + threadIdx.x; e < hi; e += 256)
        atomicAdd(&hist[((unsigned)ei[N_EDGES + e]) >> BSHIFT], 1u);
    __syncthreads();
    unsigned int* row = blkhist + (size_t)blockIdx.x * NBUCK;
    for (int i = threadIdx.x; i < NBUCK; i += 256) row[i] = hist[i];
}

// ---------- 1b: column reduce -> bucket_total[bucket] ----------
__launch_bounds__(256)
__global__ void bktA(const unsigned int* __restrict__ blkhist, unsigned int* __restrict__ total) {
    __shared__ unsigned int sh[256];
    int i = blockIdx.x;              // bucket
    int t = threadIdx.x;
    unsigned s = 0;
    for (int b = t; b < NP1; b += 256) s += blkhist[(size_t)b * NBUCK + i];
    sh[t] = s;
    __syncthreads();
    for (int off = 128; off > 0; off >>= 1) {
        if (t < off) sh[t] += sh[t + off];
        __syncthreads();
    }
    if (t == 0) total[i] = sh[0];
}

// ---------- 1c: exclusive scan of bucket totals -> bucket_base ----------
__launch_bounds__(1024)
__global__ void bktB(const unsigned int* __restrict__ total, unsigned int* __restrict__ base) {
    __shared__ unsigned int sh[1024];
    int t = threadIdx.x;
    unsigned v = (t < NBUCK) ? total[t] : 0;
    sh[t] = v;
    __syncthreads();
    for (int off = 1; off < 1024; off <<= 1) {
        unsigned a = (t >= off) ? sh[t - off] : 0;
        __syncthreads();
        sh[t] += a;
        __syncthreads();
    }
    if (t < NBUCK) base[t] = sh[t] - v;
    if (t == 0) base[NBUCK] = N_EDGES;
}

// ---------- 1d: per-bucket scan across blocks -> blkbase[bucket][block] (coalesced) ----------
__launch_bounds__(256)
__global__ void bktC(const unsigned int* __restrict__ blkhist, const unsigned int* __restrict__ base,
                     unsigned int* __restrict__ blkbase) {
    __shared__ unsigned int sh[256];
    int i = blockIdx.x;              // bucket
    int t = threadIdx.x;
    unsigned c[4];
    unsigned s = 0;
#pragma unroll
    for (int j = 0; j < 4; ++j) {
        c[j] = blkhist[(size_t)(4 * t + j) * NBUCK + i];
        s += c[j];
    }
    sh[t] = s;
    __syncthreads();
    for (int off = 1; off < 256; off <<= 1) {
        unsigned a = (t >= off) ? sh[t - off] : 0;
        __syncthreads();
        sh[t] += a;
        __syncthreads();
    }
    unsigned run = base[i] + sh[t] - s;
    unsigned int* orow = blkbase + (size_t)i * NP1 + 4 * t;
#pragma unroll
    for (int j = 0; j < 4; ++j) { orow[j] = run; run += c[j]; }
}

// ---------- 1e: deterministic scatter (zero global atomics) ----------
// pbuf entry: x = src | (dst_low7 << 17), y = ew bits
__launch_bounds__(256)
__global__ void p1scatter(const int* __restrict__ ei, const float* __restrict__ ew,
                          const unsigned int* __restrict__ blkbase, int2* __restrict__ pbuf) {
    __shared__ unsigned int bas[NBUCK];
    __shared__ unsigned int cur[NBUCK];
    int b = blockIdx.x;
    for (int i = threadIdx.x; i < NBUCK; i += 256) {
        bas[i] = blkbase[(size_t)i * NP1 + b];
        cur[i] = 0;
    }
    __syncthreads();
    int lo = b * CHUNKE;
    int hi = lo + CHUNKE; if (hi > N_EDGES) hi = N_EDGES;
    for (int e = lo + threadIdx.x; e < hi; e += 256) {
        int s = ei[e];
        unsigned d = (unsigned)ei[N_EDGES + e];
        unsigned bkt = d >> BSHIFT;
        unsigned loc = atomicAdd(&cur[bkt], 1u);
        pbuf[bas[bkt] + loc] = make_int2(s | (int)((d & 127u) << 17), __float_as_int(ew[e]));
    }
}

// ---------- phase 2a: per-bucket cnt + weighted degree via LDS ----------
__launch_bounds__(256)
__global__ void p2a(const int2* __restrict__ pbuf, const unsigned int* __restrict__ base,
                    int* __restrict__ cnt, float* __restrict__ deg) {
    __shared__ int lc[128];
    __shared__ float ld[128];
    int t = threadIdx.x;
    if (t < 128) { lc[t] = 0; ld[t] = 0.f; }
    __syncthreads();
    unsigned lo = base[blockIdx.x], hi = base[blockIdx.x + 1];
    for (unsigned i = lo + t; i < hi; i += 256) {
        int2 e = pbuf[i];
        int dl = (e.x >> 17) & 127;
        atomicAdd(&lc[dl], 1);
        atomicAdd(&ld[dl], __int_as_float(e.y));
    }
    __syncthreads();
    int d0 = blockIdx.x << BSHIFT;
    if (t < 128 && d0 + t < N_NODES) { cnt[d0 + t] = lc[t]; deg[d0 + t] = ld[t]; }
}

// ---------- dinv = rsqrt(deg + 1) ----------
__global__ void dinv_kernel(const float* __restrict__ deg, float* __restrict__ dinv) {
    int i = blockIdx.x * blockDim.x + threadIdx.x;
    if (i < N_NODES) dinv[i] = rsqrtf(deg[i] + 1.0f);
}

// ---------- phase 2b: row_ptr + final CSR with normalized weights ----------
__launch_bounds__(256)
__global__ void p2b(const int2* __restrict__ pbuf, const unsigned int* __restrict__ base,
                    const int* __restrict__ cnt, const float* __restrict__ dinv,
                    int* __restrict__ row_ptr, int2* __restrict__ ebuf) {
    __shared__ int sc[128];
    __shared__ int loff[128];
    __shared__ unsigned int lcur[128];
    int t = threadIdx.x;
    int d0 = blockIdx.x << BSHIFT;
    int nd = N_NODES - d0; if (nd > 128) nd = 128;

    int c = (t < 128 && t < nd) ? cnt[d0 + t] : 0;
    if (t < 128) sc[t] = c;
    __syncthreads();
    for (int off = 1; off < 128; off <<= 1) {
        int a = (t < 128 && t >= off) ? sc[t - off] : 0;
        __syncthreads();
        if (t < 128) sc[t] += a;
        __syncthreads();
    }
    unsigned b0 = base[blockIdx.x];
    if (t < 128) {
        int excl = sc[t] - c;
        loff[t] = excl;
        lcur[t] = 0;
        if (t < nd) row_ptr[d0 + t] = (int)(b0 + excl);
    }
    if (blockIdx.x == NBUCK - 1 && t == 0) row_ptr[N_NODES] = N_EDGES;
    __syncthreads();

    unsigned hi = base[blockIdx.x + 1];
    for (unsigned i = b0 + t; i < hi; i += 256) {
        int2 e = pbuf[i];
        int s = e.x & 0x1FFFF;
        int dl = (e.x >> 17) & 127;
        unsigned r = atomicAdd(&lcur[dl], 1u);
        float w = dinv[s] * __int_as_float(e.y) * dinv[d0 + dl];
        ebuf[b0 + loff[dl] + r] = make_int2(s, __float_as_int(w));
    }
}

// ---------- one-time W1 swizzle into MFMA B-fragment order (bf16) ----------
__global__ void wswiz_kernel(const float* __restrict__ W, unsigned short* __restrict__ wsw) {
    int idx = blockIdx.x * blockDim.x + threadIdx.x;  // 0 .. 16383
    if (idx < NF * HID) {
        int j = idx & 7;
        int lane = (idx >> 3) & 63;
        int ntile = (idx >> 9) & 3;
        int kiter = idx >> 11;
        int k = kiter * 32 + (lane >> 4) * 8 + j;
        int n = ntile * 16 + (lane & 15);
        wsw[idx] = f2bf(W[k * HID + n]);
    }
}

// ---------- h = x @ W1 via MFMA (bf16 in, fp32 acc, bf16 out, row-major) ----------
__launch_bounds__(256)
__global__ void gemm1_mfma(const float* __restrict__ x, const unsigned short* __restrict__ wsw,
                           unsigned short* __restrict__ h) {
    int t = threadIdx.x;
    int lane = t & 63;
    int wave = t >> 6;
    int m = lane & 15;
    int quad = lane >> 4;
    int rowbase = blockIdx.x * 64 + wave * 16;

    int row = rowbase + m;
    if (row >= N_NODES) row = N_NODES - 1;

    const short8* wv = (const short8*)wsw;

    f32x4 acc[4] = {{0.f,0.f,0.f,0.f},{0.f,0.f,0.f,0.f},{0.f,0.f,0.f,0.f},{0.f,0.f,0.f,0.f}};

    const float* xrow = x + (size_t)row * NF;
#pragma unroll
    for (int kiter = 0; kiter < 8; ++kiter) {
        int k0 = kiter * 32 + quad * 8;
        float4 xa = *(const float4*)&xrow[k0];
        float4 xb = *(const float4*)&xrow[k0 + 4];
        short8 a;
        a[0] = (short)f2bf(xa.x); a[1] = (short)f2bf(xa.y);
        a[2] = (short)f2bf(xa.z); a[3] = (short)f2bf(xa.w);
        a[4] = (short)f2bf(xb.x); a[5] = (short)f2bf(xb.y);
        a[6] = (short)f2bf(xb.z); a[7] = (short)f2bf(xb.w);
#pragma unroll
        for (int nt = 0; nt < 4; ++nt) {
            short8 b = wv[(kiter * 4 + nt) * 64 + lane];
            acc[nt] = __builtin_amdgcn_mfma_f32_16x16x32_bf16(a, b, acc[nt], 0, 0, 0);
        }
    }

#pragma unroll
    for (int nt = 0; nt < 4; ++nt) {
#pragma unroll
        for (int r = 0; r < 4; ++r) {
            int orow = rowbase + quad * 4 + r;
            if (orow < N_NODES) {
                int ocol = nt * 16 + m;
                h[(size_t)orow * HID + ocol] = f2bf(acc[nt][r]);
            }
        }
    }
}

// ---------- fused layer-1 aggregation + self-loop + bias + ELU + @W2 ----------
// One wave per dst. Lanes = 4 edge-groups x 16 feature-quads; each lane loads
// uint2 (4 bf16); one wave instruction gathers 4 edge rows; unrolled x4.
__launch_bounds__(256)
__global__ void fused1_kernel(const int* __restrict__ row_ptr, const int2* __restrict__ ebuf,
                              const unsigned short* __restrict__ h,
                              const float* __restrict__ dinv, const float* __restrict__ b1,
                              const float* __restrict__ W2, float* __restrict__ z) {
    int lane = threadIdx.x & 63;
    int d = (blockIdx.x * blockDim.x + threadIdx.x) >> 6;
    if (d >= N_NODES) return;

    int start = row_ptr[d];
    int end = row_ptr[d + 1];
    int f = lane & 15;
    int g = lane >> 4;

    const uint2* h64 = (const uint2*)h;

    float4 acc = make_float4(0.f, 0.f, 0.f, 0.f);

    for (int base = start; base < end; base += 64) {
        int n = end - base; if (n > 64) n = 64;
        int2 e = (lane < n) ? ebuf[base + lane] : make_int2(0, 0);
        int j = 0;
        for (; j + 16 <= n; j += 16) {
            uint2 hp[4]; float w[4];
#pragma unroll
            for (int u = 0; u < 4; ++u) {
                int idx = j + u * 4 + g;
                int s = __shfl(e.x, idx);
                w[u] = __int_as_float(__shfl(e.y, idx));
                hp[u] = h64[(size_t)s * 16 + f];
            }
#pragma unroll
            for (int u = 0; u < 4; ++u) {
                acc.x = fmaf(w[u], bfl(hp[u].x), acc.x);
                acc.y = fmaf(w[u], bfh(hp[u].x), acc.y);
                acc.z = fmaf(w[u], bfl(hp[u].y), acc.z);
                acc.w = fmaf(w[u], bfh(hp[u].y), acc.w);
            }
        }
        for (; j + 4 <= n; j += 4) {
            int idx = j + g;
            int s = __shfl(e.x, idx);
            float w = __int_as_float(__shfl(e.y, idx));
            uint2 hp = h64[(size_t)s * 16 + f];
            acc.x = fmaf(w, bfl(hp.x), acc.x);
            acc.y = fmaf(w, bfh(hp.x), acc.y);
            acc.z = fmaf(w, bfl(hp.y), acc.z);
            acc.w = fmaf(w, bfh(hp.y), acc.w);
        }
        int rem = n - j;
        if (rem > 0) {
            int idx = j + (g < rem ? g : 0);
            int s = __shfl(e.x, idx);
            float w = __int_as_float(__shfl(e.y, idx));
            if (g < rem) {
                uint2 hp = h64[(size_t)s * 16 + f];
                acc.x = fmaf(w, bfl(hp.x), acc.x);
                acc.y = fmaf(w, bfh(hp.x), acc.y);
                acc.z = fmaf(w, bfl(hp.y), acc.z);
                acc.w = fmaf(w, bfh(hp.y), acc.w);
            }
        }
    }

    acc.x += __shfl_down(acc.x, 32); acc.y += __shfl_down(acc.y, 32);
    acc.z += __shfl_down(acc.z, 32); acc.w += __shfl_down(acc.w, 32);
    acc.x += __shfl_down(acc.x, 16); acc.y += __shfl_down(acc.y, 16);
    acc.z += __shfl_down(acc.z, 16); acc.w += __shfl_down(acc.w, 16);

    float di = dinv[d];
    float d2 = di * di;
    uint2 hd = h64[(size_t)d * 16 + f];
    float4 b = *(const float4*)&b1[4 * f];
    float4 w2 = *(const float4*)&W2[4 * f];

    float v0 = acc.x + d2 * bfl(hd.x) + b.x;
    float v1 = acc.y + d2 * bfh(hd.x) + b.y;
    float v2 = acc.z + d2 * bfl(hd.y) + b.z;
    float v3 = acc.w + d2 * bfh(hd.y) + b.w;
    v0 = (v0 > 0.f) ? v0 : (__expf(v0) - 1.f);
    v1 = (v1 > 0.f) ? v1 : (__expf(v1) - 1.f);
    v2 = (v2 > 0.f) ? v2 : (__expf(v2) - 1.f);
    v3 = (v3 > 0.f) ? v3 : (__expf(v3) - 1.f);

    float p = v0 * w2.x + v1 * w2.y + v2 * w2.z + v3 * w2.w;
    p += __shfl_down(p, 8);
    p += __shfl_down(p, 4);
    p += __shfl_down(p, 2);
    p += __shfl_down(p, 1);
    if (lane == 0) z[d] = p;
}

// ---------- fused layer-2 aggregation + self-loop + bias + sigmoid ----------
__launch_bounds__(256)
__global__ void fused2_kernel(const int* __restrict__ row_ptr, const int2* __restrict__ ebuf,
                              const float* __restrict__ z, const float* __restrict__ dinv,
                              const float* __restrict__ b2, float* __restrict__ out) {
    int lane = threadIdx.x & 63;
    int d = (blockIdx.x * blockDim.x + threadIdx.x) >> 6;
    if (d >= N_NODES) return;

    int start = row_ptr[d];
    int end = row_ptr[d + 1];

    float acc = 0.0f;
    for (int i = start + lane; i < end; i += 64) {
        int2 e = ebuf[i];
        acc = fmaf(__int_as_float(e.y), z[e.x], acc);
    }
#pragma unroll
    for (int off = 32; off > 0; off >>= 1) acc += __shfl_down(acc, off);

    if (lane == 0) {
        float di = dinv[d];
        float v = acc + di * di * z[d] + b2[0];
        out[d] = 1.0f / (1.0f + __expf(-v));
    }
}

extern "C" void kernel_launch(void* const* d_in, const int* in_sizes, int n_in,
                              void* d_out, int out_size, void* d_ws, size_t ws_size,
                              hipStream_t stream) {
    const float* x  = (const float*)d_in[0];
    const int*   ei = (const int*)d_in[1];
    const float* ew = (const float*)d_in[2];
    const float* W1 = (const float*)d_in[3];
    const float* b1 = (const float*)d_in[4];
    const float* W2 = (const float*)d_in[5];
    const float* b2 = (const float*)d_in[6];
    float* out = (float*)d_out;

    char* ws = (char*)d_ws;
    unsigned int* blkhist = (unsigned int*)ws;                  ws += (size_t)NP1 * NBUCK * 4;
    unsigned int* blkbase = (unsigned int*)ws;                  ws += (size_t)NBUCK * NP1 * 4;
    unsigned int* total   = (unsigned int*)ws;                  ws += (size_t)NBUCK * 4;
    unsigned int* base    = (unsigned int*)ws;                  ws += (size_t)(NBUCK + 1) * 4;
    int*   cnt     = (int*)ws;                                  ws += (size_t)N_NODES * 4;
    float* deg     = (float*)ws;                                ws += (size_t)N_NODES * 4;
    float* dinv    = (float*)ws;                                ws += (size_t)N_NODES * 4;
    int*   row_ptr = (int*)ws;                                  ws += (size_t)(N_NODES + 1) * 4;
    int2*  pbuf    = (int2*)ws;                                 ws += (size_t)N_EDGES * 8;
    int2*  ebuf    = (int2*)ws;                                 ws += (size_t)N_EDGES * 8;
    unsigned short* h = (unsigned short*)ws;                    ws += (size_t)N_NODES * HID * 2;
    unsigned short* wsw = (unsigned short*)ws;                  ws += (size_t)NF * HID * 2;
    float* z       = (float*)ws;                                ws += (size_t)N_NODES * 4;

    p1count<<<NP1, 256, 0, stream>>>(ei, blkhist);
    bktA<<<NBUCK, 256, 0, stream>>>(blkhist, total);
    bktB<<<1, 1024, 0, stream>>>(total, base);
    bktC<<<NBUCK, 256, 0, stream>>>(blkhist, base, blkbase);
    p1scatter<<<NP1, 256, 0, stream>>>(ei, ew, blkbase, pbuf);
    p2a<<<NBUCK, 256, 0, stream>>>(pbuf, base, cnt, deg);
    dinv_kernel<<<(N_NODES + 255) / 256, 256, 0, stream>>>(deg, dinv);
    p2b<<<NBUCK, 256, 0, stream>>>(pbuf, base, cnt, dinv, row_ptr, ebuf);

    wswiz_kernel<<<(NF * HID + 255) / 256, 256, 0, stream>>>(W1, wsw);
    gemm1_mfma<<<(N_NODES + 63) / 64, 256, 0, stream>>>(x, wsw, h);

    int grid = (N_NODES * 64 + 255) / 256;
    fused1_kernel<<<grid, 256, 0, stream>>>(row_ptr, ebuf, h, dinv, b1, W2, z);
    fused2_kernel<<<grid, 256, 0, stream>>>(row_ptr, ebuf, z, dinv, b2, out);
}